// Round 10
// baseline (36.312 us; speedup 1.0000x reference)
//
#include <hip/hip_runtime.h>
#include <hip/hip_fp16.h>

// CoarseWarp via fp16 channel-last gather (K2 = round-5 verbatim; K1 v4):
//   K1: P[b][py][px][c] = (fp16) reflect-pad(ref)[b][c][py][px]   (padded 256x256)
//   K2: out[b][c][y][x] = sum_{i,j} (f32)P[b][i+sy, j+sx, c]
// K1 v4: stage RAW ref columns (reflect applied on LDS-read side -> loads are
// shift-free, 8B-aligned float2), packed fp16 pairs in LDS (ds_write_b32),
// phase C stores uint4 (1 KB / wave-instr). ~45 instr/thread vs 68 in r9.
// Accumulation f32, same i,j order; masked FMA bit-exact vs skip.

#define B_   2
#define C_   64
#define HR_  254
#define WR_  254
#define HO_  256
#define WO_  256
#define L_   (HR_ * WR_)
#define PLANE_ ((size_t)HO_ * WO_ * C_)   // halfs per batch (8.4 MB)

// ---------------- Kernel 1: transpose + reflect-pad to fp16 (v4) ------------
// Block = (b, py, 64-px x-quarter). srow32[c][f] = packed fp16 of raw ref cols
// (x0-4+2f, x0-4+2f+1). Needed rx range [x0-1, x0+62] U {1,252} is covered;
// out-of-range cols clamped to in-bounds (their slots are never read).
__global__ __launch_bounds__(256) void pad_transpose_h4(
    const float* __restrict__ ref, _Float16* __restrict__ P)
{
    __shared__ unsigned sr32[C_][37];    // 36 used + 1 pad (bank spread)

    unsigned bid  = blockIdx.x;          // [0, 2048)
    unsigned b    = bid >> 10;
    unsigned rest = bid & 1023u;
    unsigned py   = rest >> 2;
    unsigned x0   = (rest & 3u) * 64u;
    int ry = (py == 0) ? 1 : ((py == HO_ - 1) ? HR_ - 2 : (int)py - 1);

    const float* rrow = ref + ((size_t)b * C_) * (HR_ * WR_) + (size_t)ry * WR_;
    unsigned tid = threadIdx.x;

    // Phase A: 9 float2 loads/thread, covering 64 ch x 36 col-pairs.
    #pragma unroll
    for (unsigned m = 0; m < 9; ++m) {
        unsigned idx = m * 256u + tid;       // [0, 2304)
        unsigned c   = idx / 36u;
        unsigned f   = idx - c * 36u;
        int col0 = (int)x0 - 4 + 2 * (int)f;
        int cl   = col0 < 0 ? 0 : (col0 > 252 ? 252 : col0);   // even, 8B-aligned
        float2 v = *reinterpret_cast<const float2*>(rrow + (size_t)c * (HR_ * WR_) + cl);
        _Float16 h0 = (_Float16)v.x;
        _Float16 h1 = (_Float16)v.y;
        unsigned pk = (unsigned)__builtin_bit_cast(unsigned short, h0)
                    | ((unsigned)__builtin_bit_cast(unsigned short, h1) << 16);
        sr32[c][f] = pk;
    }
    __syncthreads();

    // Phase C: 2 iters x 256 thr = 512 uint4 stores (8 ch/lane, 128 B/px).
    _Float16* prow = P + ((size_t)(b * HO_ + py) * WO_ + x0) * C_;
    #pragma unroll
    for (unsigned n = 0; n < 2; ++n) {
        unsigned idx = n * 256u + tid;       // [0, 512)
        unsigned pxl = idx >> 3;             // [0,64)
        unsigned q   = idx & 7u;             // 8-ch quad
        unsigned px  = x0 + pxl;
        int rx = (px == 0) ? 1 : ((px == WO_ - 1) ? HR_ - 2 : (int)px - 1);
        unsigned k = (unsigned)(rx - (int)x0 + 4);   // u16 index within row
        unsigned short hh[8];
        #pragma unroll
        for (unsigned s = 0; s < 8; ++s) {
            const unsigned short* rowp =
                reinterpret_cast<const unsigned short*>(&sr32[q * 8u + s][0]);
            hh[s] = rowp[k];
        }
        uint4 pk;
        pk.x = (unsigned)hh[0] | ((unsigned)hh[1] << 16);
        pk.y = (unsigned)hh[2] | ((unsigned)hh[3] << 16);
        pk.z = (unsigned)hh[4] | ((unsigned)hh[5] << 16);
        pk.w = (unsigned)hh[6] | ((unsigned)hh[7] << 16);
        *reinterpret_cast<uint4*>(prow + (size_t)pxl * C_ + q * 8u) = pk;
    }
}

// ---------------- Kernel 2: batched uint4 fp16 gather + fold (round 5) ------
// Block 256 thr = 4 waves; block = (b, y, 32-px x-segment). Wave: 8 px;
// lane = (q in [0,8) pixel, cg in [0,8) 8-channel group); 9 uint4 in flight.
__global__ __launch_bounds__(256) void warp_gather4_kernel(
    const _Float16* __restrict__ P,
    const int*      __restrict__ index_map,
    float*          __restrict__ out)
{
    __shared__ unsigned sbase[3][36];     // rows y-2..y, cols x0-2 .. x0+33
    __shared__ float    slds[32][65];     // [px][ch]

    unsigned bid  = blockIdx.x;           // [0, 4096)
    unsigned b    = bid >> 11;
    unsigned rest = bid & 2047u;
    unsigned y    = rest >> 3;
    unsigned x0   = (rest & 7u) * 32u;
    unsigned tid  = threadIdx.x;

    const int* imb = index_map + (size_t)b * L_;
    if (tid < 108) {
        unsigned r    = tid / 36;         // row y-2+r  (r = 2-i)
        unsigned ccol = tid - r * 36;
        int ly = (int)y - 2 + (int)r;
        int lx = (int)(x0 + ccol) - 2;
        unsigned v = 0xFFFFFFFFu;
        if (ly >= 0 && ly < HR_ && lx >= 0 && lx < WR_) {
            unsigned src = (unsigned)imb[ly * WR_ + lx];
            unsigned sy  = src / WR_;
            unsigned sx  = src - sy * WR_;
            v = (sy * (unsigned)WO_ + sx) * (unsigned)C_;  // half-elem offset
        }
        sbase[r][ccol] = v;
    }
    __syncthreads();

    unsigned wv   = tid >> 6;
    unsigned lane = tid & 63u;
    unsigned q    = lane >> 3;            // pixel sub-index [0,8)
    unsigned cg   = lane & 7u;            // channels 8cg .. 8cg+7
    unsigned pxl  = wv * 8u + q;          // local pixel [0,32)
    const _Float16* Pp = P + (size_t)b * PLANE_;

    uint4 raw[9];
    float msk[9];
    #pragma unroll
    for (int k = 0; k < 9; ++k) {
        int i = k / 3, j = k % 3;
        unsigned v = sbase[2 - i][pxl + 2u - (unsigned)j];
        bool valid = (v != 0xFFFFFFFFu);
        unsigned off = (valid ? v : 0u)
                     + (unsigned)((i * WO_ + j) * C_) + cg * 8u;
        msk[k] = valid ? 1.0f : 0.0f;
        raw[k] = *reinterpret_cast<const uint4*>(Pp + off);
    }

    float acc[8] = {0.f, 0.f, 0.f, 0.f, 0.f, 0.f, 0.f, 0.f};
    #pragma unroll
    for (int k = 0; k < 9; ++k) {
        union { uint4 u; _Float16 h[8]; } cv;
        cv.u = raw[k];
        #pragma unroll
        for (int m = 0; m < 8; ++m) {
            acc[m] = fmaf((float)cv.h[m], msk[k], acc[m]);
        }
    }
    *reinterpret_cast<float4*>(&slds[pxl][cg * 8u]) =
        make_float4(acc[0], acc[1], acc[2], acc[3]);
    *reinterpret_cast<float4*>(&slds[pxl][cg * 8u + 4u]) =
        make_float4(acc[4], acc[5], acc[6], acc[7]);
    __syncthreads();

    // Store: lanes 0..31 = px (128 B contiguous), ch per half-wave; nt stores.
    float* ob = out + ((size_t)b * C_) * (HO_ * WO_) + (size_t)y * WO_ + x0;
    #pragma unroll
    for (unsigned it = 0; it < 8; ++it) {
        unsigned u2 = it * 256u + tid;
        unsigned px = u2 & 31u;
        unsigned ch = u2 >> 5;
        __builtin_nontemporal_store(slds[px][ch],
                                    ob + (size_t)ch * (HO_ * WO_) + px);
    }
}

extern "C" void kernel_launch(void* const* d_in, const int* in_sizes, int n_in,
                              void* d_out, int out_size, void* d_ws, size_t ws_size,
                              hipStream_t stream) {
    const float* ref       = (const float*)d_in[1];
    const int*   index_map = (const int*)d_in[2];
    float*       out       = (float*)d_out;

    _Float16* P = (_Float16*)d_ws;   // fully overwritten before use
    pad_transpose_h4<<<dim3(B_ * HO_ * 4), dim3(256), 0, stream>>>(ref, P);
    warp_gather4_kernel<<<dim3(B_ * HO_ * 8), dim3(256), 0, stream>>>(P, index_map, out);
}